// Round 5
// baseline (784.302 us; speedup 1.0000x reference)
//
#include <hip/hip_runtime.h>
#include <hip/hip_bf16.h>

#define NN 100000
#define NE 800000
// D=128, H=4, C=32

typedef __attribute__((ext_vector_type(8))) short bf16x8;
typedef __attribute__((ext_vector_type(4))) float f32x4;
typedef unsigned short ushort_t;

static __device__ __forceinline__ short f2bf(float f) {
    union { float f; unsigned u; } v; v.f = f;
    unsigned u = v.u;
    unsigned r = u + 0x7FFFu + ((u >> 16) & 1u);   // RNE
    return (short)(r >> 16);
}
static __device__ __forceinline__ float bf2f(unsigned short u) {
    union { unsigned u; float f; } v; v.u = ((unsigned)u) << 16;
    return v.f;
}

// ---------------- weight prep: W[k][c] fp32 -> Wt[c][k] bf16, 9 matrices ------------
__global__ void prep_w_k(const float* __restrict__ w_in, const float* __restrict__ Wl,
                         const float* __restrict__ Wr, const float* __restrict__ Wres,
                         ushort_t* __restrict__ wt)
{
    __shared__ float tile[32][33];
    int m = blockIdx.z;
    const float* src;
    if (m == 0)      src = w_in;
    else if (m < 4)  src = Wl + (size_t)(m - 1) * 16384;
    else if (m < 7)  src = Wr + (size_t)(m - 4) * 16384;
    else             src = Wres + (size_t)(m - 7) * 16384;
    ushort_t* dst = wt + (size_t)m * 16384;

    int tx = threadIdx.x, ty = threadIdx.y;
    int k0 = blockIdx.x * 32, c0 = blockIdx.y * 32;
    #pragma unroll
    for (int j = 0; j < 4; ++j)
        tile[ty + 8 * j][tx] = src[(size_t)(k0 + ty + 8 * j) * 128 + c0 + tx];
    __syncthreads();
    #pragma unroll
    for (int j = 0; j < 4; ++j)
        dst[(size_t)(c0 + ty + 8 * j) * 128 + k0 + tx] = (ushort_t)f2bf(tile[tx][ty + 8 * j]);
}

// ---------------- fused GEMM: up to 3 outputs per A-tile read ----------------
// A[M x 128] (fp32 or bf16) read ONCE into register fragments, then NMAT
// K-loops against bf16 W^T matrices wt[w_m]:
//   m=0 -> out0 cols [0,128) of Dout0, +bias0
//   m=1 -> out0 cols [128,256)        (requires Dout0=256)
//   m=2 -> out2 (Dout=128), +bias2
template<int A_FP32, int NMAT>
__global__ __launch_bounds__(256, 3)
void gemm_fused_k(const void* __restrict__ Av, const ushort_t* __restrict__ wt,
                  int w0, int w1, int w2,
                  const float* __restrict__ bias0, const float* __restrict__ bias2,
                  ushort_t* __restrict__ out0, int Dout0,
                  ushort_t* __restrict__ out2, int M)
{
    __shared__ short Ct[128][136];   // epilogue C-tile (reused per matrix)
    const int tid = threadIdx.x;
    const int rowBlk = blockIdx.x * 128;
    const int wave = tid >> 6;
    const int lane = tid & 63;
    const int quad = lane >> 4;
    const int lr   = lane & 15;

    const int row0 = rowBlk + wave * 32 + lr;       // A fragment rows
    const int row1 = row0 + 16;

    // ---- load A fragments once: a[ks][0] = row0, a[ks][1] = row1 ----
    bf16x8 afr[4][2];
    #pragma unroll
    for (int ks = 0; ks < 4; ++ks) {
        int kb = ks * 32 + quad * 8;
        bf16x8 a0 = (bf16x8)0, a1 = (bf16x8)0;
        if (A_FP32) {
            const float* A = (const float*)Av;
            if (row0 < M) {
                float4 v0 = *(const float4*)(A + (size_t)row0 * 128 + kb);
                float4 v1 = *(const float4*)(A + (size_t)row0 * 128 + kb + 4);
                a0[0]=f2bf(v0.x); a0[1]=f2bf(v0.y); a0[2]=f2bf(v0.z); a0[3]=f2bf(v0.w);
                a0[4]=f2bf(v1.x); a0[5]=f2bf(v1.y); a0[6]=f2bf(v1.z); a0[7]=f2bf(v1.w);
            }
            if (row1 < M) {
                float4 v0 = *(const float4*)(A + (size_t)row1 * 128 + kb);
                float4 v1 = *(const float4*)(A + (size_t)row1 * 128 + kb + 4);
                a1[0]=f2bf(v0.x); a1[1]=f2bf(v0.y); a1[2]=f2bf(v0.z); a1[3]=f2bf(v0.w);
                a1[4]=f2bf(v1.x); a1[5]=f2bf(v1.y); a1[6]=f2bf(v1.z); a1[7]=f2bf(v1.w);
            }
        } else {
            const ushort_t* A = (const ushort_t*)Av;
            if (row0 < M) a0 = *(const bf16x8*)(A + (size_t)row0 * 128 + kb);
            if (row1 < M) a1 = *(const bf16x8*)(A + (size_t)row1 * 128 + kb);
        }
        afr[ks][0] = a0; afr[ks][1] = a1;
    }

    #pragma unroll
    for (int m = 0; m < NMAT; ++m) {
        const int widx = (m == 0) ? w0 : (m == 1) ? w1 : w2;
        const ushort_t* W = wt + (size_t)widx * 16384;
        const float* bias = (m == 0) ? bias0 : ((m == 2) ? bias2 : nullptr);
        ushort_t* out = (m == 2) ? out2 : out0;
        const int Dout   = (m == 2) ? 128 : Dout0;
        const int colOff = (m == 1) ? 128 : 0;

        f32x4 acc[2][8];
        #pragma unroll
        for (int mt = 0; mt < 2; ++mt)
            #pragma unroll
            for (int nt = 0; nt < 8; ++nt) acc[mt][nt] = (f32x4)(0.0f);

        #pragma unroll
        for (int ks = 0; ks < 4; ++ks) {
            int kb = ks * 32 + quad * 8;
            #pragma unroll
            for (int nt = 0; nt < 8; ++nt) {
                bf16x8 b = *(const bf16x8*)(W + (size_t)(nt * 16 + lr) * 128 + kb);
                acc[0][nt] = __builtin_amdgcn_mfma_f32_16x16x32_bf16(afr[ks][0], b, acc[0][nt], 0, 0, 0);
                acc[1][nt] = __builtin_amdgcn_mfma_f32_16x16x32_bf16(afr[ks][1], b, acc[1][nt], 0, 0, 0);
            }
        }

        // epilogue: C/D layout col = lane&15, row = quad*4 + reg
        __syncthreads();   // prior store-pass reads of Ct complete
        #pragma unroll
        for (int mt = 0; mt < 2; ++mt)
            #pragma unroll
            for (int nt = 0; nt < 8; ++nt) {
                int col = nt * 16 + lr;
                float b = bias ? bias[col] : 0.0f;
                #pragma unroll
                for (int r = 0; r < 4; ++r) {
                    int row = wave * 32 + mt * 16 + quad * 4 + r;
                    Ct[row][col] = f2bf(acc[mt][nt][r] + b);
                }
            }
        __syncthreads();
        #pragma unroll
        for (int i = 0; i < 8; ++i) {
            int linear = tid + 256 * i;              // 2048 16B chunks
            int r  = linear >> 4;
            int c8 = (linear & 15) << 3;
            int gr = rowBlk + r;
            if (gr < M)
                *(bf16x8*)(out + (size_t)gr * Dout + colOff + c8) = *(const bf16x8*)&Ct[r][c8];
        }
    }
}

// ---------------- CSR build ----------------
__global__ void count_k(const int* __restrict__ dst, int* __restrict__ deg) {
    int e = blockIdx.x * 256 + threadIdx.x;
    if (e < NE) atomicAdd(&deg[dst[e]], 1);
}

__global__ void scan1_k(const int* __restrict__ deg, int* __restrict__ excl,
                        int* __restrict__ bsum) {
    __shared__ int buf[256];
    int i = blockIdx.x * 256 + threadIdx.x;
    int v = (i < NN) ? deg[i] : 0;
    buf[threadIdx.x] = v; __syncthreads();
    for (int off = 1; off < 256; off <<= 1) {
        int t = (threadIdx.x >= off) ? buf[threadIdx.x - off] : 0;
        __syncthreads();
        buf[threadIdx.x] += t;
        __syncthreads();
    }
    if (i < NN) excl[i] = buf[threadIdx.x] - v;
    if (threadIdx.x == 255) bsum[blockIdx.x] = buf[255];
}

__global__ void scan2_k(int* __restrict__ bsum, int nb, int* __restrict__ total) {
    __shared__ int buf[512];
    int v = (threadIdx.x < nb) ? bsum[threadIdx.x] : 0;
    buf[threadIdx.x] = v; __syncthreads();
    for (int off = 1; off < 512; off <<= 1) {
        int t = (threadIdx.x >= off) ? buf[threadIdx.x - off] : 0;
        __syncthreads();
        buf[threadIdx.x] += t;
        __syncthreads();
    }
    if (threadIdx.x < nb) bsum[threadIdx.x] = buf[threadIdx.x] - v;  // exclusive base
    if (threadIdx.x == 511) *total = buf[511];
}

__global__ void scan3_k(int* __restrict__ row_ptr, const int* __restrict__ bsum,
                        int* __restrict__ cursor) {
    int i = blockIdx.x * 256 + threadIdx.x;
    if (i < NN) {
        int v = row_ptr[i] + bsum[blockIdx.x];
        row_ptr[i] = v;
        cursor[i]  = v;
    }
}

__global__ void scatter_k(const int* __restrict__ src, const int* __restrict__ dst,
                          int* __restrict__ cursor, int* __restrict__ csr_src) {
    int e = blockIdx.x * 256 + threadIdx.x;
    if (e < NE) {
        int p = atomicAdd(&cursor[dst[e]], 1);
        csr_src[p] = src[e];
    }
}

// ---------------- GATv2 aggregate: one wave per destination node, 4 edges/iter --------
__global__ __launch_bounds__(256, 6)
void gat_aggregate_k(const ushort_t* __restrict__ xlr, const int* __restrict__ row_ptr,
                     const int* __restrict__ csr_src, const float* __restrict__ att,
                     const float* __restrict__ b_out, ushort_t* __restrict__ g)
{
    int node = blockIdx.x * 4 + (threadIdx.x >> 6);
    int lane = threadIdx.x & 63;
    int slot = lane >> 4;
    int cl   = (lane & 15) << 3;                 // channels cl..cl+7
    bf16x8 xru = *(const bf16x8*)(xlr + (size_t)node * 256 + 128 + cl);
    float xr[8], at[8];
    #pragma unroll
    for (int j = 0; j < 8; ++j) xr[j] = bf2f((ushort_t)xru[j]);
    float4 at0 = *(const float4*)(att + cl);
    float4 at1 = *(const float4*)(att + cl + 4);
    at[0] = at0.x; at[1] = at0.y; at[2] = at0.z; at[3] = at0.w;
    at[4] = at1.x; at[5] = at1.y; at[6] = at1.z; at[7] = at1.w;

    int e0 = row_ptr[node], e1 = row_ptr[node + 1];
    float acc[8] = {0.f,0.f,0.f,0.f,0.f,0.f,0.f,0.f};
    float suma = 0.f;
    for (int e = e0; e < e1; e += 4) {
        int ee = e + slot;
        bool valid = ee < e1;
        int s = csr_src[valid ? ee : e];
        bf16x8 xu = *(const bf16x8*)(xlr + (size_t)s * 256 + cl);
        float x[8];
        #pragma unroll
        for (int j = 0; j < 8; ++j) x[j] = bf2f((ushort_t)xu[j]);
        float p = 0.f;
        #pragma unroll
        for (int j = 0; j < 8; ++j) {
            float m = x[j] + xr[j];
            m = fmaxf(m, 0.2f * m);              // leaky_relu(0.2)
            p = fmaf(at[j], m, p);
        }
        p += __shfl_xor(p, 1); p += __shfl_xor(p, 2);   // per-head logit
        float a = valid ? __expf(p) : 0.f;
        suma += a;
        #pragma unroll
        for (int j = 0; j < 8; ++j) acc[j] = fmaf(a, x[j], acc[j]);
    }
    // combine the four edge slots
    suma += __shfl_xor(suma, 16); suma += __shfl_xor(suma, 32);
    #pragma unroll
    for (int j = 0; j < 8; ++j) {
        acc[j] += __shfl_xor(acc[j], 16);
        acc[j] += __shfl_xor(acc[j], 32);
    }
    if (slot == 0) {
        float inv = 1.0f / (suma + 1e-16f);
        float4 ob0 = *(const float4*)(b_out + cl);
        float4 ob1 = *(const float4*)(b_out + cl + 4);
        float ob[8] = {ob0.x, ob0.y, ob0.z, ob0.w, ob1.x, ob1.y, ob1.z, ob1.w};
        short r[8];
        #pragma unroll
        for (int j = 0; j < 8; ++j) r[j] = f2bf(fmaf(acc[j], inv, ob[j]));
        *(bf16x8*)(g + (size_t)node * 128 + cl) = *(const bf16x8*)r;
    }
}

// ---------------- PairNorm column sums (bf16 g) ----------------
__global__ void colsum_k(const ushort_t* __restrict__ g, float* __restrict__ colsum) {
    __shared__ float buf[256];
    int c = threadIdx.x & 127;
    int half = threadIdx.x >> 7;
    int r0 = blockIdx.x * 256;
    int rend = min(r0 + 256, NN);
    float s = 0.f;
    for (int r = r0 + half; r < rend; r += 2)
        s += bf2f(g[(size_t)r * 128 + c]);
    buf[threadIdx.x] = s;
    __syncthreads();
    if (threadIdx.x < 128)
        atomicAdd(&colsum[c], buf[threadIdx.x] + buf[threadIdx.x + 128]);
}

// ---------------- fused pairnorm + residual + layernorm (+relu) ----------------
__global__ __launch_bounds__(256, 4)
void finalize_k(const ushort_t* __restrict__ g, const float* __restrict__ colsum,
                const ushort_t* __restrict__ ident, const float* __restrict__ lng,
                const float* __restrict__ lnb, ushort_t* __restrict__ hout_bf,
                float* __restrict__ hout_f32, int is_final)
{
    int node = blockIdx.x * 4 + (threadIdx.x >> 6);
    int lane = threadIdx.x & 63;
    int j0 = lane * 2;
    const float invN = 1.0f / (float)NN;
    const float sqrtN = sqrtf((float)NN);

    ushort2 vu = *(const ushort2*)(g + (size_t)node * 128 + j0);
    float x0 = bf2f(vu.x) - colsum[j0] * invN;
    float x1 = bf2f(vu.y) - colsum[j0 + 1] * invN;
    float ss = x0 * x0 + x1 * x1;
    ss += __shfl_xor(ss, 1);  ss += __shfl_xor(ss, 2);  ss += __shfl_xor(ss, 4);
    ss += __shfl_xor(ss, 8);  ss += __shfl_xor(ss, 16); ss += __shfl_xor(ss, 32);
    float sc = sqrtN / (sqrtf(ss) + 1e-6f);

    ushort2 idu = *(const ushort2*)(ident + (size_t)node * 128 + j0);
    float t0 = x0 * sc + bf2f(idu.x);
    float t1 = x1 * sc + bf2f(idu.y);

    float m = t0 + t1;
    m += __shfl_xor(m, 1);  m += __shfl_xor(m, 2);  m += __shfl_xor(m, 4);
    m += __shfl_xor(m, 8);  m += __shfl_xor(m, 16); m += __shfl_xor(m, 32);
    m *= (1.0f / 128.0f);
    float d0 = t0 - m, d1 = t1 - m;
    float vv = d0 * d0 + d1 * d1;
    vv += __shfl_xor(vv, 1);  vv += __shfl_xor(vv, 2);  vv += __shfl_xor(vv, 4);
    vv += __shfl_xor(vv, 8);  vv += __shfl_xor(vv, 16); vv += __shfl_xor(vv, 32);
    vv *= (1.0f / 128.0f);
    float r = rsqrtf(vv + 1e-5f);

    float y0 = d0 * r * lng[j0]     + lnb[j0];
    float y1 = d1 * r * lng[j0 + 1] + lnb[j0 + 1];
    if (is_final) {
        float2 o; o.x = y0; o.y = y1;
        *(float2*)(hout_f32 + (size_t)node * 128 + j0) = o;
    } else {
        y0 = fmaxf(y0, 0.f); y1 = fmaxf(y1, 0.f);
        ushort2 o; o.x = (ushort_t)f2bf(y0); o.y = (ushort_t)f2bf(y1);
        *(ushort2*)(hout_bf + (size_t)node * 128 + j0) = o;
    }
}

// ---------------- host launch ----------------
extern "C" void kernel_launch(void* const* d_in, const int* in_sizes, int n_in,
                              void* d_out, int out_size, void* d_ws, size_t ws_size,
                              hipStream_t stream) {
    const float* x     = (const float*)d_in[0];
    const int*   ei    = (const int*)  d_in[1];   // [2][E]
    const float* w_in  = (const float*)d_in[2];
    const float* b_in  = (const float*)d_in[3];
    const float* Wl    = (const float*)d_in[4];
    const float* bl    = (const float*)d_in[5];
    const float* Wr    = (const float*)d_in[6];
    const float* att   = (const float*)d_in[7];
    const float* b_out = (const float*)d_in[8];
    const float* Wres  = (const float*)d_in[9];
    const float* bres  = (const float*)d_in[10];
    const float* ln_g  = (const float*)d_in[11];
    const float* ln_b  = (const float*)d_in[12];

    // workspace layout (bf16 feature buffers)
    ushort_t* h     = (ushort_t*)d_ws;                 // N*128 bf16
    ushort_t* xlr   = h + (size_t)NN * 128;            // N*256 bf16
    ushort_t* ident = xlr + (size_t)NN * 256;          // N*128 bf16
    ushort_t* g     = ident + (size_t)NN * 128;        // N*128 bf16
    ushort_t* wt    = g + (size_t)NN * 128;            // 9*128*128 bf16 (transposed weights)
    int*   row_ptr = (int*)(wt + 9 * 16384);           // N+1
    int*   cursor  = row_ptr + (NN + 1);               // N     (zeroed; also deg)
    float* colsum  = (float*)(cursor + NN);            // 3*128 (zeroed)
    int*   bsum    = (int*)(colsum + 384);             // 512
    int*   csr_src = bsum + 512;                       // E

    const int* e_src = ei;
    const int* e_dst = ei + NE;

    hipMemsetAsync(cursor, 0, (size_t)(NN + 384) * 4, stream);

    // weight transpose prep (once per call)
    prep_w_k<<<dim3(4, 4, 9), dim3(32, 8), 0, stream>>>(w_in, Wl, Wr, Wres, wt);

    // CSR build
    const int nb = (NN + 255) / 256;             // 391
    count_k  <<<NE / 256, 256, 0, stream>>>(e_dst, cursor);
    scan1_k  <<<nb, 256, 0, stream>>>(cursor, row_ptr, bsum);
    scan2_k  <<<1, 512, 0, stream>>>(bsum, nb, row_ptr + NN);
    scan3_k  <<<nb, 256, 0, stream>>>(row_ptr, bsum, cursor);
    scatter_k<<<NE / 256, 256, 0, stream>>>(e_src, e_dst, cursor, csr_src);

    const int gx = (NN + 127) / 128;             // 782

    // h = bf16(x @ w_in + b_in)
    gemm_fused_k<1, 1><<<gx, 256, 0, stream>>>(x, wt, 0, 0, 0,
                                               b_in, nullptr, h, 128, nullptr, NN);

    for (int i = 0; i < 3; ++i) {
        // xlr = bf16(h @ [Wl | Wr] + [bl | 0]); (i>0) ident = bf16(h @ Wres + bres)
        if (i == 0)
            gemm_fused_k<0, 2><<<gx, 256, 0, stream>>>(h, wt, 1, 4, 0,
                                                       bl, nullptr, xlr, 256, nullptr, NN);
        else
            gemm_fused_k<0, 3><<<gx, 256, 0, stream>>>(h, wt, 1 + i, 4 + i, 7 + (i - 1),
                                                       bl + i * 128, bres + (i - 1) * 128,
                                                       xlr, 256, ident, NN);
        gat_aggregate_k<<<NN / 4, 256, 0, stream>>>(xlr, row_ptr, csr_src,
                                                    att + i * 128, b_out + i * 128, g);
        colsum_k<<<nb, 256, 0, stream>>>(g, colsum + i * 128);
        finalize_k<<<NN / 4, 256, 0, stream>>>(g, colsum + i * 128,
                                               (i == 0) ? h : ident,
                                               ln_g + i * 128, ln_b + i * 128,
                                               h, (float*)d_out, (i == 2) ? 1 : 0);
    }
}